// Round 4
// baseline (484.502 us; speedup 1.0000x reference)
//
#include <hip/hip_runtime.h>

namespace {

constexpr int T = 512, B = 128, I = 64, H = 512, R = 8;
constexpr int CH = 16;          // time steps per x_proj chunk
constexpr int NCH = T / CH;     // 32
constexpr float ALPHA = 0.1f;

typedef _Float16 f16x8 __attribute__((ext_vector_type(8)));
typedef float f32x4 __attribute__((ext_vector_type(4)));

// DPP move: returns src taken from the lane given by ctrl (all rows/banks, bound_ctrl=1)
#define DPPF(x, ctrl) \
  __int_as_float(__builtin_amdgcn_update_dpp(0, __float_as_int(x), (ctrl), 0xF, 0xF, true))

// DPP ctrl encodings
// quad_perm [1,0,3,2] = xor1 -> 0xB1 ; quad_perm [2,3,0,1] = xor2 -> 0x4E
// row_half_mirror (lane ^ 7 within 8) -> 0x141 ; row_ror:8 (lane ^ 8 within 16) -> 0x128

__global__ __launch_bounds__(512, 1)
void ctrnn(const float* __restrict__ input, const float* __restrict__ W_in,
           const float* __restrict__ b_in, const float* __restrict__ U,
           const float* __restrict__ V, const float* __restrict__ noise,
           float* __restrict__ out) {
  const int b    = blockIdx.x;      // one block per batch element
  const int tid  = threadIdx.x;     // 0..511 == hidden index h
  const int h    = tid;
  const int lane = tid & 63;
  const int wv   = tid >> 6;        // wave 0..7
  const int l7   = lane & 7;

  // LDS: xp[16][512] (32KB) + partial[2][64] + dump[512]
  __shared__ float lds[CH * H + 2 * 64 + 512];
  float* xp   = lds;
  float* pbuf = lds + CH * H;   // 128 floats, double-buffered 64 each
  float* dump = pbuf + 128;     // scratch sink for lanes 8..63 partial writes

  // per-lane slot->r mapping: slot j holds r = j ^ m  (makes folds select-free)
  int m = ((lane & 1) << 2) | (lane & 2);
  if (lane & 4) m ^= 7;

  float vperm[8], uperm[8];
  {
    const int sig[8] = {0, 1, 2, 3, 7, 6, 5, 4};  // gather slot -> r = l7 ^ sig[j]
#pragma unroll
    for (int j = 0; j < 8; ++j) vperm[j] = V[(j ^ m) * H + h];
#pragma unroll
    for (int j = 0; j < 8; ++j) uperm[j] = U[h * R + (l7 ^ sig[j])];
  }

  // W_in fp16 B-fragments: wave wv covers h in [64*wv, 64*wv+64) -> 4 n-tiles x 2 k-tiles
  const int colh = 64 * wv + (lane & 15);
  const int krow = (lane >> 4) * 8;
  const int trow = lane & 15;
  f16x8 bfr[4][2];
  float biasf[4];
#pragma unroll
  for (int nt = 0; nt < 4; ++nt) {
    const int hh = colh + 16 * nt;
    biasf[nt] = b_in[hh];
#pragma unroll
    for (int kt = 0; kt < 2; ++kt)
#pragma unroll
      for (int j = 0; j < 8; ++j)
        bfr[nt][kt][j] = (_Float16)W_in[hh * I + kt * 32 + krow + j];
  }

  float hstate = 0.f;
  const int strideTB = B * H;
  const float* noise_b = noise + b * H + h;
  float* out_b = out + b * H + h;
  float nzp = noise_b[0];  // t=0 prefetch

  // A-chunk register prefetch (chunk 0)
  float av[2][8];
#pragma unroll
  for (int kt = 0; kt < 2; ++kt) {
    const float* src = input + (trow * B + b) * I + kt * 32 + krow;
    const float4 lo = *(const float4*)src;
    const float4 hi = *(const float4*)(src + 4);
    av[kt][0] = lo.x; av[kt][1] = lo.y; av[kt][2] = lo.z; av[kt][3] = lo.w;
    av[kt][4] = hi.x; av[kt][5] = hi.y; av[kt][6] = hi.z; av[kt][7] = hi.w;
  }

  auto step = [&](int t, int sloc) {
    const float nz = nzp;
    const int tn = (t + 1 < T) ? t + 1 : T - 1;   // clamp final prefetch
    nzp = noise_b[tn * strideTB];                  // prefetch next noise
    const float xpv = xp[sloc * H + h];            // read before barrier
    hstate += nz;
    // p[j] holds partial for r = j ^ m
    float p0 = vperm[0] * hstate, p1 = vperm[1] * hstate,
          p2 = vperm[2] * hstate, p3 = vperm[3] * hstate,
          p4 = vperm[4] * hstate, p5 = vperm[5] * hstate,
          p6 = vperm[6] * hstate, p7 = vperm[7] * hstate;
    // vector-halving folds (select-free due to r = j^m mapping)
    p0 += DPPF(p4, 0xB1); p1 += DPPF(p5, 0xB1);
    p2 += DPPF(p6, 0xB1); p3 += DPPF(p7, 0xB1);   // pair lanes xor1
    p0 += DPPF(p2, 0x4E); p1 += DPPF(p3, 0x4E);   // pair lanes xor2
    p0 += DPPF(p1, 0x141);                        // pair lanes xor7
    float sg = p0;                                // = v_partial[m] over 8-lane group
    sg += DPPF(sg, 0x128);                        // xor8
    sg += __shfl_xor(sg, 16, 64);                 // xor16
    sg += __shfl_xor(sg, 32, 64);                 // xor32 -> wave-complete v_w[m]
    float* wp = (lane < 8) ? (pbuf + (t & 1) * 64 + wv * 8 + m) : (dump + tid);
    *wp = sg;
    __syncthreads();
    // cross-wave combine: slot (w*8+r); reduce over w via xor8/16/32
    float u = pbuf[(t & 1) * 64 + lane];
    u += DPPF(u, 0x128);
    u += __shfl_xor(u, 16, 64);
    u += __shfl_xor(u, 32, 64);                   // all lanes: v_total[l7]
    // all-gather 8 values within 8-lane groups
    const float g0 = u;                           // v[l7]
    const float g1 = DPPF(g0, 0xB1);              // v[l7^1]
    const float g2 = DPPF(g0, 0x4E);              // v[l7^2]
    const float g3 = DPPF(g1, 0x4E);              // v[l7^3]
    const float g4 = DPPF(g0, 0x141);             // v[l7^7]
    const float g5 = DPPF(g1, 0x141);             // v[l7^6]
    const float g6 = DPPF(g2, 0x141);             // v[l7^5]
    const float g7 = DPPF(g3, 0x141);             // v[l7^4]
    float ra = uperm[0] * g0;
    float rb = uperm[4] * g4;
    ra = fmaf(uperm[1], g1, ra);
    rb = fmaf(uperm[5], g5, rb);
    ra = fmaf(uperm[2], g2, ra);
    rb = fmaf(uperm[6], g6, rb);
    ra = fmaf(uperm[3], g3, ra);
    rb = fmaf(uperm[7], g7, rb);
    const float rec = ra + rb;
    float hn = xpv + rec;
    hn = hn > 0.f ? hn : 0.f;
    hstate = fmaf(hstate, 1.f - ALPHA, hn * ALPHA);
    out_b[t * strideTB] = hstate;                 // fire-and-forget
  };

  for (int c = 0; c < NCH; ++c) {
    // x_proj for this chunk via MFMA (input already in av registers)
    f16x8 af[2];
#pragma unroll
    for (int kt = 0; kt < 2; ++kt)
#pragma unroll
      for (int j = 0; j < 8; ++j) af[kt][j] = (_Float16)av[kt][j];
#pragma unroll
    for (int nt = 0; nt < 4; ++nt) {
      f32x4 acc = {0.f, 0.f, 0.f, 0.f};
      acc = __builtin_amdgcn_mfma_f32_16x16x32_f16(af[0], bfr[nt][0], acc, 0, 0, 0);
      acc = __builtin_amdgcn_mfma_f32_16x16x32_f16(af[1], bfr[nt][1], acc, 0, 0, 0);
      const int hh = colh + 16 * nt;
      const int t4 = (lane >> 4) * 4;
#pragma unroll
      for (int q = 0; q < 4; ++q) xp[(t4 + q) * H + hh] = acc[q] + biasf[nt];
    }
    // issue register prefetch of next chunk's input (a full 16 steps ahead)
    if (c + 1 < NCH) {
#pragma unroll
      for (int kt = 0; kt < 2; ++kt) {
        const float* src = input + (((c + 1) * CH + trow) * B + b) * I + kt * 32 + krow;
        const float4 lo = *(const float4*)src;
        const float4 hi = *(const float4*)(src + 4);
        av[kt][0] = lo.x; av[kt][1] = lo.y; av[kt][2] = lo.z; av[kt][3] = lo.w;
        av[kt][4] = hi.x; av[kt][5] = hi.y; av[kt][6] = hi.z; av[kt][7] = hi.w;
      }
    }
    __syncthreads();  // xp visible to all waves (prev readers done: their last
                      // xp read precedes their step-15 barrier)
    const int tb = c * CH;
    for (int s = 0; s < CH; ++s) step(tb + s, s);
  }

  // hN (second tuple output)
  out[T * B * H + b * H + h] = hstate;
}

}  // namespace

extern "C" void kernel_launch(void* const* d_in, const int* in_sizes, int n_in,
                              void* d_out, int out_size, void* d_ws, size_t ws_size,
                              hipStream_t stream) {
  const float* input = (const float*)d_in[0];
  const float* W_in  = (const float*)d_in[1];
  const float* b_in  = (const float*)d_in[2];
  const float* U     = (const float*)d_in[3];
  const float* V     = (const float*)d_in[4];
  const float* noise = (const float*)d_in[5];
  float* out = (float*)d_out;
  ctrnn<<<dim3(B), dim3(512), 0, stream>>>(input, W_in, b_in, U, V, noise, out);
}

// Round 6
// 411.448 us; speedup vs baseline: 1.1776x; 1.1776x over previous
//
#include <hip/hip_runtime.h>

namespace {

constexpr int T = 512, B = 128, I = 64, H = 512, R = 8;
constexpr int CH = 16;          // time steps per x_proj chunk
constexpr int NCH = T / CH;     // 32
constexpr float ALPHA = 0.1f;

typedef _Float16 f16x8 __attribute__((ext_vector_type(8)));
typedef float f32x4 __attribute__((ext_vector_type(4)));

// DPP move: returns src taken from the lane given by ctrl (all rows/banks, bound_ctrl=1)
#define DPPF(x, ctrl) \
  __int_as_float(__builtin_amdgcn_update_dpp(0, __float_as_int(x), (ctrl), 0xF, 0xF, true))

// quad_perm [1,0,3,2] = xor1 -> 0xB1 ; quad_perm [2,3,0,1] = xor2 -> 0x4E
// row_half_mirror (lane ^ 7 within 8) -> 0x141 ; row_ror:8 (lane ^ 8 within 16) -> 0x128

__global__ __launch_bounds__(512, 1)
void ctrnn(const float* __restrict__ input, const float* __restrict__ W_in,
           const float* __restrict__ b_in, const float* __restrict__ U,
           const float* __restrict__ V, const float* __restrict__ noise,
           float* __restrict__ out) {
  const int b    = blockIdx.x;      // one block per batch element
  const int tid  = threadIdx.x;     // 0..511 == hidden index h
  const int h    = tid;
  const int lane = tid & 63;
  const int wv   = tid >> 6;        // wave 0..7
  const int l7   = lane & 7;

  // LDS: xp[16][512] (32KB) + partial[2][64] + dump[512]
  __shared__ float lds[CH * H + 2 * 64 + 512];
  float* xp   = lds;
  float* pbuf = lds + CH * H;   // 128 floats, double-buffered 64 each
  float* dump = pbuf + 128;     // scratch sink for lanes 8..63 partial writes

  // per-lane slot->r mapping: slot j holds r = j ^ m  (makes folds select-free)
  int m = ((lane & 1) << 2) | (lane & 2);
  if (lane & 4) m ^= 7;

  float vperm[8], uperm[8];
  {
    const int sig[8] = {0, 1, 2, 3, 7, 6, 5, 4};  // gather slot -> r = l7 ^ sig[j]
#pragma unroll
    for (int j = 0; j < 8; ++j) vperm[j] = V[(j ^ m) * H + h];
#pragma unroll
    for (int j = 0; j < 8; ++j) uperm[j] = U[h * R + (l7 ^ sig[j])];
  }

  // W_in fp16 B-fragments: wave wv covers h in [64*wv, 64*wv+64) -> 4 n-tiles x 2 k-tiles
  const int colh = 64 * wv + (lane & 15);
  const int krow = (lane >> 4) * 8;
  const int trow = lane & 15;
  f16x8 bfr[4][2];
  float biasf[4];
#pragma unroll
  for (int nt = 0; nt < 4; ++nt) {
    const int hh = colh + 16 * nt;
    biasf[nt] = b_in[hh];
#pragma unroll
    for (int kt = 0; kt < 2; ++kt)
#pragma unroll
      for (int j = 0; j < 8; ++j)
        bfr[nt][kt][j] = (_Float16)W_in[hh * I + kt * 32 + krow + j];
  }

  float hstate = 0.f;
  const int strideTB = B * H;
  const float* noise_b = noise + b * H + h;
  float* out_b = out + b * H + h;

  // ---- noise register pipeline: whole-chunk deep prefetch ----
  // ncur holds noise for the chunk being stepped; nnxt is loaded a full
  // chunk (~8k cyc) ahead so no HBM latency ever lands on the step chain.
  float ncur[CH], nnxt[CH];
#pragma unroll
  for (int s = 0; s < CH; ++s) ncur[s] = noise_b[s * strideTB];

  // A-chunk register prefetch (chunk 0)
  float av[2][8];
#pragma unroll
  for (int kt = 0; kt < 2; ++kt) {
    const float* src = input + (trow * B + b) * I + kt * 32 + krow;
    const float4 lo = *(const float4*)src;
    const float4 hi = *(const float4*)(src + 4);
    av[kt][0] = lo.x; av[kt][1] = lo.y; av[kt][2] = lo.z; av[kt][3] = lo.w;
    av[kt][4] = hi.x; av[kt][5] = hi.y; av[kt][6] = hi.z; av[kt][7] = hi.w;
  }

  auto step = [&](int t, int sloc, float nz) {
    const float xpv = xp[sloc * H + h];            // LDS read, off critical path
    hstate += nz;
    // p[j] holds partial for r = j ^ m
    float p0 = vperm[0] * hstate, p1 = vperm[1] * hstate,
          p2 = vperm[2] * hstate, p3 = vperm[3] * hstate,
          p4 = vperm[4] * hstate, p5 = vperm[5] * hstate,
          p6 = vperm[6] * hstate, p7 = vperm[7] * hstate;
    // vector-halving folds (select-free due to r = j^m mapping)
    p0 += DPPF(p4, 0xB1); p1 += DPPF(p5, 0xB1);
    p2 += DPPF(p6, 0xB1); p3 += DPPF(p7, 0xB1);   // pair lanes xor1
    p0 += DPPF(p2, 0x4E); p1 += DPPF(p3, 0x4E);   // pair lanes xor2
    p0 += DPPF(p1, 0x141);                        // pair lanes xor7
    float sg = p0;                                // = v_partial[m] over 8-lane group
    sg += DPPF(sg, 0x128);                        // xor8
    sg += __shfl_xor(sg, 16, 64);                 // xor16
    sg += __shfl_xor(sg, 32, 64);                 // xor32 -> wave-complete v_w[m]
    float* wp = (lane < 8) ? (pbuf + (t & 1) * 64 + wv * 8 + m) : (dump + tid);
    *wp = sg;
    __syncthreads();
    // cross-wave combine: slot (w*8+r); reduce over w via xor8/16/32
    float u = pbuf[(t & 1) * 64 + lane];
    u += DPPF(u, 0x128);
    u += __shfl_xor(u, 16, 64);
    u += __shfl_xor(u, 32, 64);                   // all lanes: v_total[l7]
    // all-gather 8 values within 8-lane groups
    const float g0 = u;                           // v[l7]
    const float g1 = DPPF(g0, 0xB1);              // v[l7^1]
    const float g2 = DPPF(g0, 0x4E);              // v[l7^2]
    const float g3 = DPPF(g1, 0x4E);              // v[l7^3]
    const float g4 = DPPF(g0, 0x141);             // v[l7^7]
    const float g5 = DPPF(g1, 0x141);             // v[l7^6]
    const float g6 = DPPF(g2, 0x141);             // v[l7^5]
    const float g7 = DPPF(g3, 0x141);             // v[l7^4]
    float ra = uperm[0] * g0;
    float rb = uperm[4] * g4;
    ra = fmaf(uperm[1], g1, ra);
    rb = fmaf(uperm[5], g5, rb);
    ra = fmaf(uperm[2], g2, ra);
    rb = fmaf(uperm[6], g6, rb);
    ra = fmaf(uperm[3], g3, ra);
    rb = fmaf(uperm[7], g7, rb);
    const float rec = ra + rb;
    float hn = xpv + rec;
    hn = hn > 0.f ? hn : 0.f;
    hstate = fmaf(hstate, 1.f - ALPHA, hn * ALPHA);
    out_b[t * strideTB] = hstate;                 // fire-and-forget
  };

  for (int c = 0; c < NCH; ++c) {
    // issue next chunk's noise loads first (independent, deepest prefetch)
    if (c + 1 < NCH) {
      const float* nb = noise_b + (c + 1) * CH * strideTB;
#pragma unroll
      for (int s = 0; s < CH; ++s) nnxt[s] = nb[s * strideTB];
    }
    // x_proj for this chunk via MFMA (input already in av registers)
    f16x8 af[2];
#pragma unroll
    for (int kt = 0; kt < 2; ++kt)
#pragma unroll
      for (int j = 0; j < 8; ++j) af[kt][j] = (_Float16)av[kt][j];
#pragma unroll
    for (int nt = 0; nt < 4; ++nt) {
      f32x4 acc = {0.f, 0.f, 0.f, 0.f};
      acc = __builtin_amdgcn_mfma_f32_16x16x32_f16(af[0], bfr[nt][0], acc, 0, 0, 0);
      acc = __builtin_amdgcn_mfma_f32_16x16x32_f16(af[1], bfr[nt][1], acc, 0, 0, 0);
      const int hh = colh + 16 * nt;
      const int t4 = (lane >> 4) * 4;
#pragma unroll
      for (int q = 0; q < 4; ++q) xp[(t4 + q) * H + hh] = acc[q] + biasf[nt];
    }
    // issue register prefetch of next chunk's input (a full 16 steps ahead)
    if (c + 1 < NCH) {
#pragma unroll
      for (int kt = 0; kt < 2; ++kt) {
        const float* src = input + (((c + 1) * CH + trow) * B + b) * I + kt * 32 + krow;
        const float4 lo = *(const float4*)src;
        const float4 hi = *(const float4*)(src + 4);
        av[kt][0] = lo.x; av[kt][1] = lo.y; av[kt][2] = lo.z; av[kt][3] = lo.w;
        av[kt][4] = hi.x; av[kt][5] = hi.y; av[kt][6] = hi.z; av[kt][7] = hi.w;
      }
    }
    __syncthreads();  // xp visible to all waves (prev readers done: their last
                      // xp read precedes their step-15 barrier)
    const int tb = c * CH;
#pragma unroll
    for (int s = 0; s < CH; ++s) step(tb + s, s, ncur[s]);
    if (c + 1 < NCH) {
#pragma unroll
      for (int s = 0; s < CH; ++s) ncur[s] = nnxt[s];
    }
  }

  // hN (second tuple output)
  out[T * B * H + b * H + h] = hstate;
}

}  // namespace

extern "C" void kernel_launch(void* const* d_in, const int* in_sizes, int n_in,
                              void* d_out, int out_size, void* d_ws, size_t ws_size,
                              hipStream_t stream) {
  const float* input = (const float*)d_in[0];
  const float* W_in  = (const float*)d_in[1];
  const float* b_in  = (const float*)d_in[2];
  const float* U     = (const float*)d_in[3];
  const float* V     = (const float*)d_in[4];
  const float* noise = (const float*)d_in[5];
  float* out = (float*)d_out;
  ctrnn<<<dim3(B), dim3(512), 0, stream>>>(input, W_in, b_in, U, V, noise, out);
}